// Round 6
// baseline (93.897 us; speedup 1.0000x reference)
//
#include <hip/hip_runtime.h>

#define BB 8
#define NN 4096
#define HH 256
#define KOUT 1024
#define LCAP 256   // max cluster size guard (E[size]=65, max ~<110)

// Single fused kernel: 2048 blocks x 256 threads; 4 waves/block = 4 output rows,
// all in the same batch (1024 rows/batch, 4 | 1024). Each block scans its
// batch's labels once (L2-resident) and builds the <=4 member lists it needs in
// LDS, then each wave runs single-pass softmax attention (k/v projected on the
// fly; scores bounded so no max-shift needed) + out_proj + 256-wide MLP.
__global__ __launch_bounds__(256) void k_all(
    const float* __restrict__ x, const int* __restrict__ labels,
    const float* __restrict__ Wq, const float* __restrict__ bq,
    const float* __restrict__ Wk, const float* __restrict__ bk,
    const float* __restrict__ Wv, const float* __restrict__ bv,
    const float* __restrict__ Wo, const float* __restrict__ bo,
    const float* __restrict__ W1, const float* __restrict__ b1,
    const float* __restrict__ W2, const float* __restrict__ b2,
    float* __restrict__ out)
{
    int tid  = threadIdx.x;
    int w    = tid >> 6;        // wave 0..3
    int lane = tid & 63;
    int row  = blockIdx.x * 4 + w;        // 0 .. B*KOUT-1
    int b = row >> 10, n = row & (KOUT - 1);
    int l = labels[b * NN + n];           // wave-uniform

    __shared__ int cl[4];
    __shared__ int cnt[4];
    __shared__ int list[4][LCAP];
    if (lane == 0) { cl[w] = (l < 0) ? -2 : l; cnt[w] = 0; }  // -2: never matches
    __syncthreads();

    // build the 4 member lists: coalesced label scan, LDS-atomic compaction
    {
        int t0 = cl[0], t1 = cl[1], t2 = cl[2], t3 = cl[3];
        const int* lb = labels + b * NN;
        #pragma unroll
        for (int jj = 0; jj < 16; jj++) {
            int i = jj * 256 + tid;
            int li = lb[i];
            if (li == t0) { int p = atomicAdd(&cnt[0], 1); if (p < LCAP) list[0][p] = i; }
            if (li == t1) { int p = atomicAdd(&cnt[1], 1); if (p < LCAP) list[1][p] = i; }
            if (li == t2) { int p = atomicAdd(&cnt[2], 1); if (p < LCAP) list[2][p] = i; }
            if (li == t3) { int p = atomicAdd(&cnt[3], 1); if (p < LCAP) list[3][p] = i; }
        }
    }

    // q for this row (all lanes redundantly; broadcast loads)
    const float* xr = x + (b * NN + n) * 3;
    float x0 = xr[0], x1 = xr[1], x2 = xr[2];
    float q0 = bq[0] + x0 * Wq[0] + x1 * Wq[1] + x2 * Wq[2];
    float q1 = bq[1] + x0 * Wq[3] + x1 * Wq[4] + x2 * Wq[5];
    float q2 = bq[2] + x0 * Wq[6] + x1 * Wq[7] + x2 * Wq[8];
    __syncthreads();

    float c0 = 0.f, c1 = 0.f, c2 = 0.f;
    if (l >= 0) {
        const float scale = 0.5773502691896258f;  // 1/sqrt(3)
        int C = min(cnt[w], LCAP);
        float dsum = 0.f;
        for (int i = lane; i < C; i += 64) {
            int m = list[w][i];
            const float* xm = x + (b * NN + m) * 3;
            float y0 = xm[0], y1 = xm[1], y2 = xm[2];
            float k0 = bk[0] + y0 * Wk[0] + y1 * Wk[1] + y2 * Wk[2];
            float k1 = bk[1] + y0 * Wk[3] + y1 * Wk[4] + y2 * Wk[5];
            float k2 = bk[2] + y0 * Wk[6] + y1 * Wk[7] + y2 * Wk[8];
            float wgt = __expf((q0 * k0 + q1 * k1 + q2 * k2) * scale);
            float v0 = bv[0] + y0 * Wv[0] + y1 * Wv[1] + y2 * Wv[2];
            float v1 = bv[1] + y0 * Wv[3] + y1 * Wv[4] + y2 * Wv[5];
            float v2 = bv[2] + y0 * Wv[6] + y1 * Wv[7] + y2 * Wv[8];
            dsum += wgt; c0 += wgt * v0; c1 += wgt * v1; c2 += wgt * v2;
        }
        #pragma unroll
        for (int d = 32; d > 0; d >>= 1) {
            dsum += __shfl_xor(dsum, d, 64);
            c0   += __shfl_xor(c0, d, 64);
            c1   += __shfl_xor(c1, d, 64);
            c2   += __shfl_xor(c2, d, 64);
        }
        float inv = 1.f / dsum;
        c0 *= inv; c1 *= inv; c2 *= inv;
    }

    // out_proj (wave-uniform weights -> scalar loads)
    float o0 = bo[0] + c0 * Wo[0] + c1 * Wo[1] + c2 * Wo[2];
    float o1 = bo[1] + c0 * Wo[3] + c1 * Wo[4] + c2 * Wo[5];
    float o2 = bo[2] + c0 * Wo[6] + c1 * Wo[7] + c2 * Wo[8];

    // MLP: 4 hidden units per lane + wave reduction
    float y0 = 0.f, y1 = 0.f, y2 = 0.f;
    #pragma unroll
    for (int t = 0; t < 4; t++) {
        int j = lane + 64 * t;
        float h = fmaxf(W1[j * 3 + 0] * o0 + W1[j * 3 + 1] * o1 + W1[j * 3 + 2] * o2 + b1[j], 0.f);
        y0 += h * W2[j];
        y1 += h * W2[HH + j];
        y2 += h * W2[2 * HH + j];
    }
    #pragma unroll
    for (int d = 32; d > 0; d >>= 1) {
        y0 += __shfl_xor(y0, d, 64);
        y1 += __shfl_xor(y1, d, 64);
        y2 += __shfl_xor(y2, d, 64);
    }
    if (lane == 0) {
        out[row * 3 + 0] = y0 + b2[0];
        out[row * 3 + 1] = y1 + b2[1];
        out[row * 3 + 2] = y2 + b2[2];
    }
}

extern "C" void kernel_launch(void* const* d_in, const int* in_sizes, int n_in,
                              void* d_out, int out_size, void* d_ws, size_t ws_size,
                              hipStream_t stream) {
    const float* x      = (const float*)d_in[0];
    const int*   labels = (const int*)d_in[1];
    const float* Wq = (const float*)d_in[2];
    const float* bq = (const float*)d_in[3];
    const float* Wk = (const float*)d_in[4];
    const float* bk = (const float*)d_in[5];
    const float* Wv = (const float*)d_in[6];
    const float* bv = (const float*)d_in[7];
    const float* Wo = (const float*)d_in[8];
    const float* bo = (const float*)d_in[9];
    const float* W1 = (const float*)d_in[10];
    const float* b1 = (const float*)d_in[11];
    const float* W2 = (const float*)d_in[12];
    const float* b2 = (const float*)d_in[13];
    float* out = (float*)d_out;

    k_all<<<(BB * KOUT) / 4, 256, 0, stream>>>(x, labels,
                                               Wq, bq, Wk, bk, Wv, bv,
                                               Wo, bo, W1, b1, W2, b2, out);
}